// Round 1
// baseline (550.064 us; speedup 1.0000x reference)
//
#include <hip/hip_runtime.h>
#include <math.h>

#define N    20000
#define E    200000
#define EP   220000   // E + N self loops
#define F_IN 23
#define D1   960
#define H1   8
#define C1   120
#define KPL  15       // channels per lane: C1 / 8

// ---------------- kernel 1: xl1 = x@W1l+b1l, xr1 = x@W1r+b1r ----------------
#define TB_NODES 8
__global__ __launch_bounds__(960)
void k_transform1(const float* __restrict__ x,
                  const float* __restrict__ W1l, const float* __restrict__ b1l,
                  const float* __restrict__ W1r, const float* __restrict__ b1r,
                  float* __restrict__ xl1, float* __restrict__ xr1) {
  __shared__ float xs[TB_NODES][F_IN + 1];
  int base = blockIdx.x * TB_NODES;
  int tid = threadIdx.x;
  if (tid < TB_NODES * F_IN) {
    int n = tid / F_IN, f = tid % F_IN;
    int node = base + n;
    xs[n][f] = (node < N) ? x[node * F_IN + f] : 0.f;
  }
  __syncthreads();
  int col = tid;  // 0..959
  float bl = b1l[col], br = b1r[col];
  float accl[TB_NODES], accr[TB_NODES];
#pragma unroll
  for (int n = 0; n < TB_NODES; n++) { accl[n] = bl; accr[n] = br; }
  for (int k = 0; k < F_IN; k++) {
    float wl = W1l[k * D1 + col];
    float wr = W1r[k * D1 + col];
#pragma unroll
    for (int n = 0; n < TB_NODES; n++) {
      accl[n] = fmaf(xs[n][k], wl, accl[n]);
      accr[n] = fmaf(xs[n][k], wr, accr[n]);
    }
  }
#pragma unroll
  for (int n = 0; n < TB_NODES; n++) {
    int node = base + n;
    if (node < N) {
      xl1[node * D1 + col] = accl[n];
      xr1[node * D1 + col] = accr[n];
    }
  }
}

// ---------------- CSR build over dst ----------------
__global__ void k_count(const int* __restrict__ ei, int* __restrict__ deg) {
  int id = blockIdx.x * blockDim.x + threadIdx.x;
  if (id >= EP) return;
  int dst = (id < E) ? ei[E + id] : (id - E);
  atomicAdd(&deg[dst], 1);
}

// single-block exclusive scan of deg[0..N) -> off[0..N], also copies to cursor
__global__ __launch_bounds__(1024)
void k_scan(const int* __restrict__ deg, int* __restrict__ off,
            int* __restrict__ cursor) {
  __shared__ int wsum[16];
  __shared__ int carry_s;
  int tid = threadIdx.x, lane = tid & 63, wid = tid >> 6;
  if (tid == 0) carry_s = 0;
  __syncthreads();
  for (int base = 0; base < N; base += 1024) {
    int i = base + tid;
    int v = (i < N) ? deg[i] : 0;
    int incl = v;
#pragma unroll
    for (int d = 1; d < 64; d <<= 1) {
      int t = __shfl_up(incl, d, 64);
      if (lane >= d) incl += t;
    }
    if (lane == 63) wsum[wid] = incl;
    __syncthreads();
    if (tid == 0) {
      int acc = carry_s;
#pragma unroll
      for (int w = 0; w < 16; w++) { int t = wsum[w]; wsum[w] = acc; acc += t; }
      carry_s = acc;
    }
    __syncthreads();
    int excl = incl - v + wsum[wid];
    if (i < N) { off[i] = excl; cursor[i] = excl; }
    __syncthreads();
  }
  if (tid == 0) off[N] = carry_s;
}

__global__ void k_scatter(const int* __restrict__ ei, int* __restrict__ cursor,
                          int* __restrict__ eidx) {
  int id = blockIdx.x * blockDim.x + threadIdx.x;
  if (id >= EP) return;
  int dst = (id < E) ? ei[E + id] : (id - E);
  int pos = atomicAdd(&cursor[dst], 1);
  eidx[pos] = id;
}

// ---------------- fused layer1 aggregate + relu + layer2 transform ----------
// one wave per dst node; lane -> (head h = lane>>3, g = lane&7), 15 chans each
__global__ __launch_bounds__(256)
void k_l1agg(const int* __restrict__ ei, const int* __restrict__ off,
             const int* __restrict__ eidx,
             const float* __restrict__ xl1, const float* __restrict__ xr1,
             const float* __restrict__ att1, const float* __restrict__ bias1,
             const float* __restrict__ W2l, const float* __restrict__ b2l,
             const float* __restrict__ W2r, const float* __restrict__ b2r,
             float* __restrict__ xl2, float* __restrict__ xr2) {
  int node = blockIdx.x * 4 + (threadIdx.x >> 6);
  if (node >= N) return;
  int lane = threadIdx.x & 63;
  int cbase = (lane >> 3) * C1 + (lane & 7);  // this lane's first channel

  float xrr[KPL], attr[KPL];
  const float* xrp = xr1 + node * D1 + cbase;
  const float* atp = att1 + cbase;
#pragma unroll
  for (int k = 0; k < KPL; k++) { xrr[k] = xrp[8 * k]; attr[k] = atp[8 * k]; }

  float m = -INFINITY, d = 0.f;
  float o[KPL];
#pragma unroll
  for (int k = 0; k < KPL; k++) o[k] = 0.f;

  int p1 = off[node + 1];
  for (int p = off[node]; p < p1; p++) {
    int id = eidx[p];
    int src = (id < E) ? ei[id] : (id - E);
    const float* xlp = xl1 + src * D1 + cbase;
    float xlv[KPL];
    float pe = 0.f;
#pragma unroll
    for (int k = 0; k < KPL; k++) {
      float xv = xlp[8 * k];
      xlv[k] = xv;
      float s = xv + xrr[k];
      s = (s > 0.f) ? s : 0.2f * s;
      pe = fmaf(s, attr[k], pe);
    }
    // per-head (8-lane group) reduction of the attention logit
    pe += __shfl_xor(pe, 1, 64);
    pe += __shfl_xor(pe, 2, 64);
    pe += __shfl_xor(pe, 4, 64);
    // online softmax
    if (pe > m) {
      float sc = expf(m - pe);   // m=-inf on first edge -> 0
      d *= sc;
#pragma unroll
      for (int k = 0; k < KPL; k++) o[k] *= sc;
      m = pe;
    }
    float w = expf(pe - m);
    d += w;
#pragma unroll
    for (int k = 0; k < KPL; k++) o[k] = fmaf(w, xlv[k], o[k]);
  }

  float inv = 1.f / (d + 1e-16f);
  // h1 = relu(out + bias1), fused GEMV with W2l/W2r
  float pl = 0.f, pr = 0.f;
#pragma unroll
  for (int k = 0; k < KPL; k++) {
    float hv = o[k] * inv + bias1[cbase + 8 * k];
    hv = fmaxf(hv, 0.f);
    pl = fmaf(hv, W2l[cbase + 8 * k], pl);
    pr = fmaf(hv, W2r[cbase + 8 * k], pr);
  }
#pragma unroll
  for (int dx = 1; dx < 64; dx <<= 1) {
    pl += __shfl_xor(pl, dx, 64);
    pr += __shfl_xor(pr, dx, 64);
  }
  if (lane == 0) {
    xl2[node] = pl + b2l[0];
    xr2[node] = pr + b2r[0];
  }
}

// ---------------- layer 2 aggregate: scalar online softmax per node ---------
__global__ void k_l2agg(const int* __restrict__ ei, const int* __restrict__ off,
                        const int* __restrict__ eidx,
                        const float* __restrict__ xl2, const float* __restrict__ xr2,
                        const float* __restrict__ att2, const float* __restrict__ bias2,
                        float* __restrict__ out) {
  int node = blockIdx.x * blockDim.x + threadIdx.x;
  if (node >= N) return;
  float xr = xr2[node];
  float a2 = att2[0];
  float m = -INFINITY, d = 0.f, o = 0.f;
  int p1 = off[node + 1];
  for (int p = off[node]; p < p1; p++) {
    int id = eidx[p];
    int src = (id < E) ? ei[id] : (id - E);
    float xl = xl2[src];
    float s = xl + xr;
    s = (s > 0.f) ? s : 0.2f * s;
    float e = s * a2;
    if (e > m) { float sc = expf(m - e); d *= sc; o *= sc; m = e; }
    float w = expf(e - m);
    d += w;
    o = fmaf(w, xl, o);
  }
  out[node] = o / (d + 1e-16f) + bias2[0];
}

extern "C" void kernel_launch(void* const* d_in, const int* in_sizes, int n_in,
                              void* d_out, int out_size, void* d_ws, size_t ws_size,
                              hipStream_t stream) {
  const float* x     = (const float*)d_in[0];
  const int*   ei    = (const int*)d_in[1];
  const float* W1l   = (const float*)d_in[2];
  const float* b1l   = (const float*)d_in[3];
  const float* W1r   = (const float*)d_in[4];
  const float* b1r   = (const float*)d_in[5];
  const float* att1  = (const float*)d_in[6];
  const float* bias1 = (const float*)d_in[7];
  const float* W2l   = (const float*)d_in[8];
  const float* b2l   = (const float*)d_in[9];
  const float* W2r   = (const float*)d_in[10];
  const float* b2r   = (const float*)d_in[11];
  const float* att2  = (const float*)d_in[12];
  const float* bias2 = (const float*)d_in[13];
  float* out = (float*)d_out;

  char* ws = (char*)d_ws;
  size_t off_b = 0;
  auto alloc = [&](size_t bytes) {
    size_t cur = off_b;
    off_b += (bytes + 255) & ~(size_t)255;
    return (void*)(ws + cur);
  };
  float* xl1   = (float*)alloc((size_t)N * D1 * sizeof(float));
  float* xr1   = (float*)alloc((size_t)N * D1 * sizeof(float));
  int*   deg   = (int*)alloc((size_t)N * sizeof(int));
  int*   offp  = (int*)alloc((size_t)(N + 1) * sizeof(int));
  int*   curs  = (int*)alloc((size_t)N * sizeof(int));
  int*   eidx  = (int*)alloc((size_t)EP * sizeof(int));
  float* xl2   = (float*)alloc((size_t)N * sizeof(float));
  float* xr2   = (float*)alloc((size_t)N * sizeof(float));
  (void)ws_size; (void)in_sizes; (void)n_in; (void)out_size;

  hipMemsetAsync(deg, 0, (size_t)N * sizeof(int), stream);

  k_transform1<<<(N + TB_NODES - 1) / TB_NODES, 960, 0, stream>>>(
      x, W1l, b1l, W1r, b1r, xl1, xr1);

  k_count<<<(EP + 255) / 256, 256, 0, stream>>>(ei, deg);
  k_scan<<<1, 1024, 0, stream>>>(deg, offp, curs);
  k_scatter<<<(EP + 255) / 256, 256, 0, stream>>>(ei, curs, eidx);

  k_l1agg<<<(N + 3) / 4, 256, 0, stream>>>(
      ei, offp, eidx, xl1, xr1, att1, bias1, W2l, b2l, W2r, b2r, xl2, xr2);

  k_l2agg<<<(N + 255) / 256, 256, 0, stream>>>(
      ei, offp, eidx, xl2, xr2, att2, bias2, out);
}

// Round 2
// 239.864 us; speedup vs baseline: 2.2932x; 2.2932x over previous
//
#include <hip/hip_runtime.h>
#include <math.h>

#define N    20000
#define E    200000
#define EP   220000   // E + N self loops
#define F_IN 23
#define D1   960
#define H1   8
#define C1   120
#define KPL  15       // channels per lane: C1 / 8

// ---------------- kernel 1: xl1 = x@W1l+b1l, xr1 = x@W1r+b1r ----------------
// 250 blocks x 80 nodes. Each thread owns one output column and keeps its
// 23+23 W coefficients in registers; x staged in LDS 16 nodes at a time.
// Non-temporal stores keep the 153 MB output stream from thrashing L2.
#define T1_BLOCKS 250
#define T1_NPB    80      // nodes per block (N / T1_BLOCKS)
#define T1_TILE   16
__global__ __launch_bounds__(960)
void k_transform1(const float* __restrict__ x,
                  const float* __restrict__ W1l, const float* __restrict__ b1l,
                  const float* __restrict__ W1r, const float* __restrict__ b1r,
                  float* __restrict__ xl1, float* __restrict__ xr1) {
  int col = threadIdx.x;  // 0..959
  float wl[F_IN], wr[F_IN];
#pragma unroll
  for (int k = 0; k < F_IN; k++) {
    wl[k] = W1l[k * D1 + col];
    wr[k] = W1r[k * D1 + col];
  }
  float blv = b1l[col], brv = b1r[col];
  __shared__ float xs[T1_TILE][F_IN];
  int nbase = blockIdx.x * T1_NPB;
  for (int t = 0; t < T1_NPB; t += T1_TILE) {
    int tid = threadIdx.x;
    if (tid < T1_TILE * F_IN) {  // 368 threads stage the x tile
      int n = tid / F_IN, f = tid % F_IN;
      xs[n][f] = x[(size_t)(nbase + t + n) * F_IN + f];
    }
    __syncthreads();
#pragma unroll
    for (int n = 0; n < T1_TILE; n++) {
      float al = blv, ar = brv;
#pragma unroll
      for (int k = 0; k < F_IN; k++) {
        float xv = xs[n][k];
        al = fmaf(xv, wl[k], al);
        ar = fmaf(xv, wr[k], ar);
      }
      size_t o = (size_t)(nbase + t + n) * D1 + col;
      __builtin_nontemporal_store(al, &xl1[o]);
      __builtin_nontemporal_store(ar, &xr1[o]);
    }
    __syncthreads();
  }
}

// ---------------- CSR build over dst ----------------
__global__ void k_count(const int* __restrict__ ei, int* __restrict__ deg) {
  int id = blockIdx.x * blockDim.x + threadIdx.x;
  if (id >= EP) return;
  int dst = (id < E) ? ei[E + id] : (id - E);
  atomicAdd(&deg[dst], 1);
}

// single-block exclusive scan of deg[0..N) -> off[0..N], also copies to cursor
__global__ __launch_bounds__(1024)
void k_scan(const int* __restrict__ deg, int* __restrict__ off,
            int* __restrict__ cursor) {
  __shared__ int wsum[16];
  __shared__ int carry_s;
  int tid = threadIdx.x, lane = tid & 63, wid = tid >> 6;
  if (tid == 0) carry_s = 0;
  __syncthreads();
  for (int base = 0; base < N; base += 1024) {
    int i = base + tid;
    int v = (i < N) ? deg[i] : 0;
    int incl = v;
#pragma unroll
    for (int d = 1; d < 64; d <<= 1) {
      int t = __shfl_up(incl, d, 64);
      if (lane >= d) incl += t;
    }
    if (lane == 63) wsum[wid] = incl;
    __syncthreads();
    if (tid == 0) {
      int acc = carry_s;
#pragma unroll
      for (int w = 0; w < 16; w++) { int t = wsum[w]; wsum[w] = acc; acc += t; }
      carry_s = acc;
    }
    __syncthreads();
    int excl = incl - v + wsum[wid];
    if (i < N) { off[i] = excl; cursor[i] = excl; }
    __syncthreads();
  }
  if (tid == 0) off[N] = carry_s;
}

__global__ void k_scatter(const int* __restrict__ ei, int* __restrict__ cursor,
                          int* __restrict__ eidx) {
  int id = blockIdx.x * blockDim.x + threadIdx.x;
  if (id >= EP) return;
  int dst = (id < E) ? ei[E + id] : (id - E);
  int pos = atomicAdd(&cursor[dst], 1);
  eidx[pos] = id;
}

// ---------------- fused layer1 aggregate + relu + layer2 transform ----------
// one wave per dst node; lane -> (head h = lane>>3, g = lane&7), 15 chans each
__global__ __launch_bounds__(256)
void k_l1agg(const int* __restrict__ ei, const int* __restrict__ off,
             const int* __restrict__ eidx,
             const float* __restrict__ xl1, const float* __restrict__ xr1,
             const float* __restrict__ att1, const float* __restrict__ bias1,
             const float* __restrict__ W2l, const float* __restrict__ b2l,
             const float* __restrict__ W2r, const float* __restrict__ b2r,
             float* __restrict__ xl2, float* __restrict__ xr2) {
  int node = blockIdx.x * 4 + (threadIdx.x >> 6);
  if (node >= N) return;
  int lane = threadIdx.x & 63;
  int cbase = (lane >> 3) * C1 + (lane & 7);  // this lane's first channel

  float xrr[KPL], attr[KPL];
  const float* xrp = xr1 + (size_t)node * D1 + cbase;
  const float* atp = att1 + cbase;
#pragma unroll
  for (int k = 0; k < KPL; k++) { xrr[k] = xrp[8 * k]; attr[k] = atp[8 * k]; }

  float m = -INFINITY, d = 0.f;
  float o[KPL];
#pragma unroll
  for (int k = 0; k < KPL; k++) o[k] = 0.f;

  int p1 = off[node + 1];
  for (int p = off[node]; p < p1; p++) {
    int id = eidx[p];
    int src = (id < E) ? ei[id] : (id - E);
    const float* xlp = xl1 + (size_t)src * D1 + cbase;
    float xlv[KPL];
    float pe = 0.f;
#pragma unroll
    for (int k = 0; k < KPL; k++) {
      float xv = xlp[8 * k];
      xlv[k] = xv;
      float s = xv + xrr[k];
      s = (s > 0.f) ? s : 0.2f * s;
      pe = fmaf(s, attr[k], pe);
    }
    // per-head (8-lane group) reduction of the attention logit
    pe += __shfl_xor(pe, 1, 64);
    pe += __shfl_xor(pe, 2, 64);
    pe += __shfl_xor(pe, 4, 64);
    // online softmax
    if (pe > m) {
      float sc = expf(m - pe);   // m=-inf on first edge -> 0
      d *= sc;
#pragma unroll
      for (int k = 0; k < KPL; k++) o[k] *= sc;
      m = pe;
    }
    float w = expf(pe - m);
    d += w;
#pragma unroll
    for (int k = 0; k < KPL; k++) o[k] = fmaf(w, xlv[k], o[k]);
  }

  float inv = 1.f / (d + 1e-16f);
  // h1 = relu(out + bias1), fused GEMV with W2l/W2r
  float pl = 0.f, pr = 0.f;
#pragma unroll
  for (int k = 0; k < KPL; k++) {
    float hv = o[k] * inv + bias1[cbase + 8 * k];
    hv = fmaxf(hv, 0.f);
    pl = fmaf(hv, W2l[cbase + 8 * k], pl);
    pr = fmaf(hv, W2r[cbase + 8 * k], pr);
  }
#pragma unroll
  for (int dx = 1; dx < 64; dx <<= 1) {
    pl += __shfl_xor(pl, dx, 64);
    pr += __shfl_xor(pr, dx, 64);
  }
  if (lane == 0) {
    xl2[node] = pl + b2l[0];
    xr2[node] = pr + b2r[0];
  }
}

// ---------------- layer 2 aggregate: scalar online softmax per node ---------
__global__ void k_l2agg(const int* __restrict__ ei, const int* __restrict__ off,
                        const int* __restrict__ eidx,
                        const float* __restrict__ xl2, const float* __restrict__ xr2,
                        const float* __restrict__ att2, const float* __restrict__ bias2,
                        float* __restrict__ out) {
  int node = blockIdx.x * blockDim.x + threadIdx.x;
  if (node >= N) return;
  float xr = xr2[node];
  float a2 = att2[0];
  float m = -INFINITY, d = 0.f, o = 0.f;
  int p1 = off[node + 1];
  for (int p = off[node]; p < p1; p++) {
    int id = eidx[p];
    int src = (id < E) ? ei[id] : (id - E);
    float xl = xl2[src];
    float s = xl + xr;
    s = (s > 0.f) ? s : 0.2f * s;
    float e = s * a2;
    if (e > m) { float sc = expf(m - e); d *= sc; o *= sc; m = e; }
    float w = expf(e - m);
    d += w;
    o = fmaf(w, xl, o);
  }
  out[node] = o / (d + 1e-16f) + bias2[0];
}

extern "C" void kernel_launch(void* const* d_in, const int* in_sizes, int n_in,
                              void* d_out, int out_size, void* d_ws, size_t ws_size,
                              hipStream_t stream) {
  const float* x     = (const float*)d_in[0];
  const int*   ei    = (const int*)d_in[1];
  const float* W1l   = (const float*)d_in[2];
  const float* b1l   = (const float*)d_in[3];
  const float* W1r   = (const float*)d_in[4];
  const float* b1r   = (const float*)d_in[5];
  const float* att1  = (const float*)d_in[6];
  const float* bias1 = (const float*)d_in[7];
  const float* W2l   = (const float*)d_in[8];
  const float* b2l   = (const float*)d_in[9];
  const float* W2r   = (const float*)d_in[10];
  const float* b2r   = (const float*)d_in[11];
  const float* att2  = (const float*)d_in[12];
  const float* bias2 = (const float*)d_in[13];
  float* out = (float*)d_out;

  char* ws = (char*)d_ws;
  size_t off_b = 0;
  auto alloc = [&](size_t bytes) {
    size_t cur = off_b;
    off_b += (bytes + 255) & ~(size_t)255;
    return (void*)(ws + cur);
  };
  float* xl1   = (float*)alloc((size_t)N * D1 * sizeof(float));
  float* xr1   = (float*)alloc((size_t)N * D1 * sizeof(float));
  int*   deg   = (int*)alloc((size_t)N * sizeof(int));
  int*   offp  = (int*)alloc((size_t)(N + 1) * sizeof(int));
  int*   curs  = (int*)alloc((size_t)N * sizeof(int));
  int*   eidx  = (int*)alloc((size_t)EP * sizeof(int));
  float* xl2   = (float*)alloc((size_t)N * sizeof(float));
  float* xr2   = (float*)alloc((size_t)N * sizeof(float));
  (void)ws_size; (void)in_sizes; (void)n_in; (void)out_size;

  hipMemsetAsync(deg, 0, (size_t)N * sizeof(int), stream);

  k_transform1<<<T1_BLOCKS, 960, 0, stream>>>(
      x, W1l, b1l, W1r, b1r, xl1, xr1);

  k_count<<<(EP + 255) / 256, 256, 0, stream>>>(ei, deg);
  k_scan<<<1, 1024, 0, stream>>>(deg, offp, curs);
  k_scatter<<<(EP + 255) / 256, 256, 0, stream>>>(ei, curs, eidx);

  k_l1agg<<<(N + 3) / 4, 256, 0, stream>>>(
      ei, offp, eidx, xl1, xr1, att1, bias1, W2l, b2l, W2r, b2r, xl2, xr2);

  k_l2agg<<<(N + 255) / 256, 256, 0, stream>>>(
      ei, offp, eidx, xl2, xr2, att2, bias2, out);
}

// Round 3
// 187.647 us; speedup vs baseline: 2.9314x; 1.2783x over previous
//
#include <hip/hip_runtime.h>
#include <hip/hip_fp16.h>
#include <math.h>

#define N    20000
#define E    200000
#define EP   220000   // E + N self loops
#define F_IN 23
#define D1   960
#define H1   8
#define C1   120
#define KPL  15       // real channels per lane
#define PC   16       // padded channels per lane (15 + 1 zero pad)
#define ROW  1024     // PC * 64 halves per node row (2048 B)

// ---------------- kernel 1: fp16 permuted xl1/xr1 ----------------
// 960 threads; thread tid owns permuted slot: rlane=tid/15, k=tid%15.
// channel c = (rlane>>3)*120 + (rlane&7)*15 + k, stored at row*1024 + rlane*16 + k.
#define T1_BLOCKS 250
#define T1_NPB    80
#define T1_TILE   16
__global__ __launch_bounds__(960)
void k_transform1(const float* __restrict__ x,
                  const float* __restrict__ W1l, const float* __restrict__ b1l,
                  const float* __restrict__ W1r, const float* __restrict__ b1r,
                  __half* __restrict__ xl1, __half* __restrict__ xr1) {
  int tid = threadIdx.x;
  int rlane = tid / 15;
  int k = tid - rlane * 15;
  int c = (rlane >> 3) * C1 + (rlane & 7) * KPL + k;   // real channel
  int pidx = rlane * PC + k;                            // permuted slot
  float wl[F_IN], wr[F_IN];
#pragma unroll
  for (int f = 0; f < F_IN; f++) {
    wl[f] = W1l[f * D1 + c];
    wr[f] = W1r[f * D1 + c];
  }
  float blv = b1l[c], brv = b1r[c];
  __shared__ float xs[T1_TILE][F_IN];
  int nbase = blockIdx.x * T1_NPB;
  for (int t = 0; t < T1_NPB; t += T1_TILE) {
    if (tid < T1_TILE * F_IN) {
      int n = tid / F_IN, f = tid % F_IN;
      xs[n][f] = x[(size_t)(nbase + t + n) * F_IN + f];
    }
    __syncthreads();
#pragma unroll
    for (int n = 0; n < T1_TILE; n++) {
      float al = blv, ar = brv;
#pragma unroll
      for (int f = 0; f < F_IN; f++) {
        float xv = xs[n][f];
        al = fmaf(xv, wl[f], al);
        ar = fmaf(xv, wr[f], ar);
      }
      size_t o = (size_t)(nbase + t + n) * ROW + pidx;
      __builtin_nontemporal_store(__half_as_ushort(__float2half(al)),
                                  (unsigned short*)&xl1[o]);
      __builtin_nontemporal_store(__half_as_ushort(__float2half(ar)),
                                  (unsigned short*)&xr1[o]);
      if (tid < 64) {  // zero the pad slot (k==15) of each lane
        size_t po = (size_t)(nbase + t + n) * ROW + tid * PC + 15;
        __builtin_nontemporal_store((unsigned short)0, (unsigned short*)&xl1[po]);
        __builtin_nontemporal_store((unsigned short)0, (unsigned short*)&xr1[po]);
      }
    }
    __syncthreads();
  }
}

// ---------------- CSR build over dst ----------------
__global__ void k_count(const int* __restrict__ ei, int* __restrict__ deg) {
  int id = blockIdx.x * blockDim.x + threadIdx.x;
  if (id >= EP) return;
  int dst = (id < E) ? ei[E + id] : (id - E);
  atomicAdd(&deg[dst], 1);
}

__global__ __launch_bounds__(1024)
void k_scan(const int* __restrict__ deg, int* __restrict__ off,
            int* __restrict__ cursor) {
  __shared__ int wsum[16];
  __shared__ int carry_s;
  int tid = threadIdx.x, lane = tid & 63, wid = tid >> 6;
  if (tid == 0) carry_s = 0;
  __syncthreads();
  for (int base = 0; base < N; base += 1024) {
    int i = base + tid;
    int v = (i < N) ? deg[i] : 0;
    int incl = v;
#pragma unroll
    for (int d = 1; d < 64; d <<= 1) {
      int t = __shfl_up(incl, d, 64);
      if (lane >= d) incl += t;
    }
    if (lane == 63) wsum[wid] = incl;
    __syncthreads();
    if (tid == 0) {
      int acc = carry_s;
#pragma unroll
      for (int w = 0; w < 16; w++) { int t = wsum[w]; wsum[w] = acc; acc += t; }
      carry_s = acc;
    }
    __syncthreads();
    int excl = incl - v + wsum[wid];
    if (i < N) { off[i] = excl; cursor[i] = excl; }
    __syncthreads();
  }
  if (tid == 0) off[N] = carry_s;
}

// scatter: store src node id directly (removes one indirection downstream)
__global__ void k_scatter(const int* __restrict__ ei, int* __restrict__ cursor,
                          int* __restrict__ srcs) {
  int id = blockIdx.x * blockDim.x + threadIdx.x;
  if (id >= EP) return;
  int dst, src;
  if (id < E) { dst = ei[E + id]; src = ei[id]; }
  else        { dst = id - E;     src = id - E; }
  int pos = atomicAdd(&cursor[dst], 1);
  srcs[pos] = src;
}

// ---------------- fused layer1 aggregate + relu + layer2 transform ----------
__device__ inline void h8_to_f(uint4 u, float* f) {
  const __half2* hp = (const __half2*)&u;
#pragma unroll
  for (int j = 0; j < 4; j++) {
    float2 v = __half22float2(hp[j]);
    f[2 * j] = v.x; f[2 * j + 1] = v.y;
  }
}

__global__ __launch_bounds__(256)
void k_l1agg(const int* __restrict__ off, const int* __restrict__ srcs,
             const __half* __restrict__ xl1, const __half* __restrict__ xr1,
             const float* __restrict__ att1, const float* __restrict__ bias1,
             const float* __restrict__ W2l, const float* __restrict__ b2l,
             const float* __restrict__ W2r, const float* __restrict__ b2r,
             float* __restrict__ xl2, float* __restrict__ xr2) {
  int node = blockIdx.x * 4 + (threadIdx.x >> 6);
  if (node >= N) return;
  int lane = threadIdx.x & 63;
  int h = lane >> 3, r8 = lane & 7;
  int cbase = h * C1 + r8 * KPL;   // first real channel of this lane

  // this lane's xr row chunk + attention weights (pad slot = 0)
  float xrr[PC], attr[PC];
  {
    const uint4* rp = (const uint4*)(xr1 + (size_t)node * ROW + lane * PC);
    uint4 a = rp[0], b = rp[1];
    h8_to_f(a, xrr); h8_to_f(b, xrr + 8);
#pragma unroll
    for (int k = 0; k < KPL; k++) attr[k] = att1[cbase + k];
    attr[15] = 0.f;
  }

  float m = -INFINITY, d = 0.f;
  float o[PC];
#pragma unroll
  for (int k = 0; k < PC; k++) o[k] = 0.f;

  int p0 = off[node], p1 = off[node + 1];
  // prefetch first edge (every node has >=1 edge: self loop)
  int src = srcs[p0];
  const uint4* rp = (const uint4*)(xl1 + ((size_t)src << 10)) + (lane << 1);
  uint4 a0 = rp[0], b0 = rp[1];

  for (int p = p0; p < p1; p++) {
    uint4 ca = a0, cb = b0;
    // branch-free prefetch of next edge (clamped; redundant last iter is cached)
    int pn = (p + 1 < p1) ? p + 1 : p;
    int nsrc = srcs[pn];
    const uint4* np = (const uint4*)(xl1 + ((size_t)nsrc << 10)) + (lane << 1);
    a0 = np[0]; b0 = np[1];

    float xv[PC];
    h8_to_f(ca, xv); h8_to_f(cb, xv + 8);
    float pe = 0.f;
#pragma unroll
    for (int k = 0; k < PC; k++) {
      float s = xv[k] + xrr[k];
      s = (s > 0.f) ? s : 0.2f * s;
      pe = fmaf(s, attr[k], pe);
    }
    pe += __shfl_xor(pe, 1, 64);
    pe += __shfl_xor(pe, 2, 64);
    pe += __shfl_xor(pe, 4, 64);
    if (pe > m) {
      float sc = __expf(m - pe);   // m=-inf first edge -> 0
      d *= sc;
#pragma unroll
      for (int k = 0; k < PC; k++) o[k] *= sc;
      m = pe;
    }
    float w = __expf(pe - m);
    d += w;
#pragma unroll
    for (int k = 0; k < PC; k++) o[k] = fmaf(w, xv[k], o[k]);
  }

  float inv = 1.f / (d + 1e-16f);
  float pl = 0.f, pr = 0.f;
#pragma unroll
  for (int k = 0; k < KPL; k++) {
    float hv = o[k] * inv + bias1[cbase + k];
    hv = fmaxf(hv, 0.f);
    pl = fmaf(hv, W2l[cbase + k], pl);
    pr = fmaf(hv, W2r[cbase + k], pr);
  }
#pragma unroll
  for (int dx = 1; dx < 64; dx <<= 1) {
    pl += __shfl_xor(pl, dx, 64);
    pr += __shfl_xor(pr, dx, 64);
  }
  if (lane == 0) {
    xl2[node] = pl + b2l[0];
    xr2[node] = pr + b2r[0];
  }
}

// ---------------- layer 2 aggregate ----------------
__global__ void k_l2agg(const int* __restrict__ off, const int* __restrict__ srcs,
                        const float* __restrict__ xl2, const float* __restrict__ xr2,
                        const float* __restrict__ att2, const float* __restrict__ bias2,
                        float* __restrict__ out) {
  int node = blockIdx.x * blockDim.x + threadIdx.x;
  if (node >= N) return;
  float xr = xr2[node];
  float a2 = att2[0];
  float m = -INFINITY, d = 0.f, o = 0.f;
  int p1 = off[node + 1];
  for (int p = off[node]; p < p1; p++) {
    float xl = xl2[srcs[p]];
    float s = xl + xr;
    s = (s > 0.f) ? s : 0.2f * s;
    float e = s * a2;
    if (e > m) { float sc = __expf(m - e); d *= sc; o *= sc; m = e; }
    float w = __expf(e - m);
    d += w;
    o = fmaf(w, xl, o);
  }
  out[node] = o / (d + 1e-16f) + bias2[0];
}

extern "C" void kernel_launch(void* const* d_in, const int* in_sizes, int n_in,
                              void* d_out, int out_size, void* d_ws, size_t ws_size,
                              hipStream_t stream) {
  const float* x     = (const float*)d_in[0];
  const int*   ei    = (const int*)d_in[1];
  const float* W1l   = (const float*)d_in[2];
  const float* b1l   = (const float*)d_in[3];
  const float* W1r   = (const float*)d_in[4];
  const float* b1r   = (const float*)d_in[5];
  const float* att1  = (const float*)d_in[6];
  const float* bias1 = (const float*)d_in[7];
  const float* W2l   = (const float*)d_in[8];
  const float* b2l   = (const float*)d_in[9];
  const float* W2r   = (const float*)d_in[10];
  const float* b2r   = (const float*)d_in[11];
  const float* att2  = (const float*)d_in[12];
  const float* bias2 = (const float*)d_in[13];
  float* out = (float*)d_out;

  char* ws = (char*)d_ws;
  size_t off_b = 0;
  auto alloc = [&](size_t bytes) {
    size_t cur = off_b;
    off_b += (bytes + 255) & ~(size_t)255;
    return (void*)(ws + cur);
  };
  __half* xl1 = (__half*)alloc((size_t)N * ROW * sizeof(__half));
  __half* xr1 = (__half*)alloc((size_t)N * ROW * sizeof(__half));
  int*   deg  = (int*)alloc((size_t)N * sizeof(int));
  int*   offp = (int*)alloc((size_t)(N + 1) * sizeof(int));
  int*   curs = (int*)alloc((size_t)N * sizeof(int));
  int*   srcs = (int*)alloc((size_t)EP * sizeof(int));
  float* xl2  = (float*)alloc((size_t)N * sizeof(float));
  float* xr2  = (float*)alloc((size_t)N * sizeof(float));
  (void)ws_size; (void)in_sizes; (void)n_in; (void)out_size;

  hipMemsetAsync(deg, 0, (size_t)N * sizeof(int), stream);

  k_transform1<<<T1_BLOCKS, 960, 0, stream>>>(
      x, W1l, b1l, W1r, b1r, xl1, xr1);

  k_count<<<(EP + 255) / 256, 256, 0, stream>>>(ei, deg);
  k_scan<<<1, 1024, 0, stream>>>(deg, offp, curs);
  k_scatter<<<(EP + 255) / 256, 256, 0, stream>>>(ei, curs, srcs);

  k_l1agg<<<(N + 3) / 4, 256, 0, stream>>>(
      offp, srcs, xl1, xr1, att1, bias1, W2l, b2l, W2r, b2r, xl2, xr2);

  k_l2agg<<<(N + 255) / 256, 256, 0, stream>>>(
      offp, srcs, xl2, xr2, att2, bias2, out);
}

// Round 5
// 184.094 us; speedup vs baseline: 2.9879x; 1.0193x over previous
//
#include <hip/hip_runtime.h>
#include <hip/hip_fp16.h>
#include <math.h>

#define N    20000
#define E    200000
#define EP   220000   // E + N self loops
#define F_IN 23
#define D1   960
#define H1   8
#define C1   120
#define KPL  15       // real channels per lane
#define PC   16       // padded channels per lane
#define ROW  1024     // halves per node row (2048 B)

typedef _Float16 f16x2 __attribute__((ext_vector_type(2)));

__device__ inline float fdot2(__half2 a, __half2 b, float c) {
#if __has_builtin(__builtin_amdgcn_fdot2)
  f16x2 av, bv;
  __builtin_memcpy(&av, &a, 4);
  __builtin_memcpy(&bv, &b, 4);
  return __builtin_amdgcn_fdot2(av, bv, c, false);
#else
  float2 af = __half22float2(a), bf = __half22float2(b);
  return fmaf(af.x, bf.x, fmaf(af.y, bf.y, c));
#endif
}

// packed half2 max (ROCm 7.2 lacks __hmax2) -> v_pk_max_f16
__device__ inline __half2 hmax2(__half2 a, __half2 b) {
  f16x2 av, bv;
  __builtin_memcpy(&av, &a, 4);
  __builtin_memcpy(&bv, &b, 4);
  f16x2 rv = __builtin_elementwise_max(av, bv);
  __half2 r;
  __builtin_memcpy(&r, &rv, 4);
  return r;
}

// ---------------- fused: transform1 (blocks 0..T1_BLOCKS) + count ----------
// transform: 512 threads; thread j owns channel pair of rlane=j>>3, kp=j&7:
// k0=2kp, k1=2kp+1 (k1==15 is the zero pad). f32 compute, packed 4B NT store.
#define T1_BLOCKS 200
#define T1_NPB    100
#define T1_TILE   20
#define CNT_BLOCKS 430   // ceil(EP/512)
__global__ __launch_bounds__(512)
void k_t1_count(const float* __restrict__ x,
                const float* __restrict__ W1l, const float* __restrict__ b1l,
                const float* __restrict__ W1r, const float* __restrict__ b1r,
                __half* __restrict__ xl1, __half* __restrict__ xr1,
                const int* __restrict__ ei, int* __restrict__ deg) {
  int tid = threadIdx.x;
  if (blockIdx.x >= T1_BLOCKS) {
    int id = (blockIdx.x - T1_BLOCKS) * 512 + tid;
    if (id < EP) {
      int dst = (id < E) ? ei[E + id] : (id - E);
      atomicAdd(&deg[dst], 1);
    }
    return;
  }
  int rlane = tid >> 3, kp = tid & 7;
  int c0 = (rlane >> 3) * C1 + (rlane & 7) * KPL + 2 * kp;
  bool hasK1 = (kp < 7);
  float wl0[F_IN], wl1[F_IN], wr0[F_IN], wr1[F_IN];
#pragma unroll
  for (int f = 0; f < F_IN; f++) {
    wl0[f] = W1l[f * D1 + c0];
    wr0[f] = W1r[f * D1 + c0];
    wl1[f] = hasK1 ? W1l[f * D1 + c0 + 1] : 0.f;
    wr1[f] = hasK1 ? W1r[f * D1 + c0 + 1] : 0.f;
  }
  float bl0 = b1l[c0], br0 = b1r[c0];
  float bl1 = hasK1 ? b1l[c0 + 1] : 0.f;
  float br1 = hasK1 ? b1r[c0 + 1] : 0.f;

  __shared__ float xs[T1_TILE][F_IN];
  int nbase = blockIdx.x * T1_NPB;
  unsigned int* xl1u = (unsigned int*)xl1;
  unsigned int* xr1u = (unsigned int*)xr1;
  for (int t = 0; t < T1_NPB; t += T1_TILE) {
    if (tid < T1_TILE * F_IN) {
      int n = tid / F_IN, f = tid - n * F_IN;
      xs[n][f] = x[(size_t)(nbase + t + n) * F_IN + f];
    }
    __syncthreads();
    for (int n = 0; n < T1_TILE; n++) {
      float a0 = bl0, a1 = bl1, r0 = br0, r1 = br1;
#pragma unroll
      for (int f = 0; f < F_IN; f++) {
        float xv = xs[n][f];
        a0 = fmaf(xv, wl0[f], a0);
        a1 = fmaf(xv, wl1[f], a1);
        r0 = fmaf(xv, wr0[f], r0);
        r1 = fmaf(xv, wr1[f], r1);
      }
      size_t o = (size_t)(nbase + t + n) * 512 + tid;
      unsigned int ul = ((unsigned int)__half_as_ushort(__float2half(a1)) << 16)
                      | __half_as_ushort(__float2half(a0));
      unsigned int ur = ((unsigned int)__half_as_ushort(__float2half(r1)) << 16)
                      | __half_as_ushort(__float2half(r0));
      __builtin_nontemporal_store(ul, &xl1u[o]);
      __builtin_nontemporal_store(ur, &xr1u[o]);
    }
    __syncthreads();
  }
}

// ---------------- scan: whole deg[] in LDS, 20 elems/thread ----------------
#define SC_TOT 20480   // 1024 * 20
__global__ __launch_bounds__(1024)
void k_scan(const int* __restrict__ deg, int* __restrict__ off,
            int* __restrict__ cursor) {
  __shared__ int buf[SC_TOT];
  __shared__ int parts[1024];
  __shared__ int wsum[17];
  int tid = threadIdx.x;
  for (int i = tid; i < SC_TOT; i += 1024) buf[i] = (i < N) ? deg[i] : 0;
  __syncthreads();
  int base = tid * 20;
  int loc[20];
  int run = 0;
#pragma unroll
  for (int e = 0; e < 20; e++) { loc[e] = run; run += buf[base + e]; }
  parts[tid] = run;
  __syncthreads();
  int lane = tid & 63, wid = tid >> 6;
  int v = parts[tid];
  int incl = v;
#pragma unroll
  for (int d = 1; d < 64; d <<= 1) {
    int t = __shfl_up(incl, d, 64);
    if (lane >= d) incl += t;
  }
  if (lane == 63) wsum[wid] = incl;
  __syncthreads();
  if (tid == 0) {
    int acc = 0;
#pragma unroll
    for (int w = 0; w < 16; w++) { int t = wsum[w]; wsum[w] = acc; acc += t; }
    wsum[16] = acc;
  }
  __syncthreads();
  int texcl = incl - v + wsum[wid];
#pragma unroll
  for (int e = 0; e < 20; e++) buf[base + e] = texcl + loc[e];
  __syncthreads();
  for (int i = tid; i < N; i += 1024) {
    int t = buf[i];
    off[i] = t;
    cursor[i] = t;
  }
  if (tid == 0) off[N] = wsum[16];
}

// scatter: store src node id directly
__global__ __launch_bounds__(512)
void k_scatter(const int* __restrict__ ei, int* __restrict__ cursor,
               int* __restrict__ srcs) {
  int id = blockIdx.x * 512 + threadIdx.x;
  if (id >= EP) return;
  int dst, src;
  if (id < E) { dst = ei[E + id]; src = ei[id]; }
  else        { dst = id - E;     src = id - E; }
  int pos = atomicAdd(&cursor[dst], 1);
  srcs[pos] = src;
}

// ---------------- fused layer1 aggregate + relu + layer2 transform ----------
union Rowu {
  uint4 u[2];
  __half2 h[8];
};

__global__ __launch_bounds__(256)
void k_l1agg(const int* __restrict__ off, const int* __restrict__ srcs,
             const __half* __restrict__ xl1, const __half* __restrict__ xr1,
             const float* __restrict__ att1, const float* __restrict__ bias1,
             const float* __restrict__ W2l, const float* __restrict__ b2l,
             const float* __restrict__ W2r, const float* __restrict__ b2r,
             float* __restrict__ xl2, float* __restrict__ xr2) {
  int node = blockIdx.x * 4 + (threadIdx.x >> 6);
  if (node >= N) return;
  int lane = threadIdx.x & 63;
  int cbase = (lane >> 3) * C1 + (lane & 7) * KPL;

  Rowu xr;
  {
    const uint4* rp = (const uint4*)(xr1 + ((size_t)node << 10)) + (lane << 1);
    xr.u[0] = rp[0]; xr.u[1] = rp[1];
  }
  __half2 at2[8];
#pragma unroll
  for (int j = 0; j < 7; j++)
    at2[j] = __floats2half2_rn(att1[cbase + 2 * j], att1[cbase + 2 * j + 1]);
  at2[7] = __floats2half2_rn(att1[cbase + 14], 0.f);

  const __half2 c02 = __float2half2_rn(0.2f);
  __half2 o2[8];
#pragma unroll
  for (int j = 0; j < 8; j++) o2[j] = __float2half2_rn(0.f);
  float m = -INFINITY, d = 0.f;

  int p0 = off[node], p1 = off[node + 1];
  int sA = srcs[p0];
  int sB = srcs[(p0 + 1 < p1) ? p0 + 1 : p0];
  Rowu rA, rB;
  {
    const uint4* rp = (const uint4*)(xl1 + ((size_t)sA << 10)) + (lane << 1);
    rA.u[0] = rp[0]; rA.u[1] = rp[1];
    const uint4* np = (const uint4*)(xl1 + ((size_t)sB << 10)) + (lane << 1);
    rB.u[0] = np[0]; rB.u[1] = np[1];
  }

  for (int p = p0; p < p1; p++) {
    Rowu cur = rA;
    rA = rB;
    int pn = (p + 2 < p1) ? p + 2 : p1 - 1;
    int sn = srcs[pn];
    const uint4* np = (const uint4*)(xl1 + ((size_t)sn << 10)) + (lane << 1);
    rB.u[0] = np[0]; rB.u[1] = np[1];

    float pe = 0.f;
#pragma unroll
    for (int j = 0; j < 8; j++) {
      __half2 s = __hadd2(cur.h[j], xr.h[j]);
      __half2 l = hmax2(s, __hmul2(c02, s));   // leaky = max(s, 0.2s)
      pe = fdot2(l, at2[j], pe);
    }
    pe += __shfl_xor(pe, 1, 64);
    pe += __shfl_xor(pe, 2, 64);
    pe += __shfl_xor(pe, 4, 64);
    if (pe > m) {
      float sc = __expf(m - pe);   // m=-inf first edge -> 0
      d *= sc;
      __half2 s2 = __float2half2_rn(sc);
#pragma unroll
      for (int j = 0; j < 8; j++) o2[j] = __hmul2(o2[j], s2);
      m = pe;
    }
    float w = __expf(pe - m);
    d += w;
    __half2 w2 = __float2half2_rn(w);
#pragma unroll
    for (int j = 0; j < 8; j++) o2[j] = __hfma2(w2, cur.h[j], o2[j]);
  }

  float inv = 1.f / (d + 1e-16f);
  float pl = 0.f, pr = 0.f;
#pragma unroll
  for (int j = 0; j < 8; j++) {
    float2 of = __half22float2(o2[j]);
    int k0 = 2 * j;
    float hv = fmaf(of.x, inv, bias1[cbase + k0]);
    hv = fmaxf(hv, 0.f);
    pl = fmaf(hv, W2l[cbase + k0], pl);
    pr = fmaf(hv, W2r[cbase + k0], pr);
    if (j < 7) {
      float hv2 = fmaf(of.y, inv, bias1[cbase + k0 + 1]);
      hv2 = fmaxf(hv2, 0.f);
      pl = fmaf(hv2, W2l[cbase + k0 + 1], pl);
      pr = fmaf(hv2, W2r[cbase + k0 + 1], pr);
    }
  }
#pragma unroll
  for (int dx = 1; dx < 64; dx <<= 1) {
    pl += __shfl_xor(pl, dx, 64);
    pr += __shfl_xor(pr, dx, 64);
  }
  if (lane == 0) {
    xl2[node] = pl + b2l[0];
    xr2[node] = pr + b2r[0];
  }
}

// ---------------- layer 2 aggregate ----------------
__global__ void k_l2agg(const int* __restrict__ off, const int* __restrict__ srcs,
                        const float* __restrict__ xl2, const float* __restrict__ xr2,
                        const float* __restrict__ att2, const float* __restrict__ bias2,
                        float* __restrict__ out) {
  int node = blockIdx.x * blockDim.x + threadIdx.x;
  if (node >= N) return;
  float xr = xr2[node];
  float a2 = att2[0];
  float m = -INFINITY, d = 0.f, o = 0.f;
  int p1 = off[node + 1];
  for (int p = off[node]; p < p1; p++) {
    float xl = xl2[srcs[p]];
    float s = xl + xr;
    s = fmaxf(s, 0.2f * s);
    float e = s * a2;
    if (e > m) { float sc = __expf(m - e); d *= sc; o *= sc; m = e; }
    float w = __expf(e - m);
    d += w;
    o = fmaf(w, xl, o);
  }
  out[node] = o / (d + 1e-16f) + bias2[0];
}

extern "C" void kernel_launch(void* const* d_in, const int* in_sizes, int n_in,
                              void* d_out, int out_size, void* d_ws, size_t ws_size,
                              hipStream_t stream) {
  const float* x     = (const float*)d_in[0];
  const int*   ei    = (const int*)d_in[1];
  const float* W1l   = (const float*)d_in[2];
  const float* b1l   = (const float*)d_in[3];
  const float* W1r   = (const float*)d_in[4];
  const float* b1r   = (const float*)d_in[5];
  const float* att1  = (const float*)d_in[6];
  const float* bias1 = (const float*)d_in[7];
  const float* W2l   = (const float*)d_in[8];
  const float* b2l   = (const float*)d_in[9];
  const float* W2r   = (const float*)d_in[10];
  const float* b2r   = (const float*)d_in[11];
  const float* att2  = (const float*)d_in[12];
  const float* bias2 = (const float*)d_in[13];
  float* out = (float*)d_out;

  char* ws = (char*)d_ws;
  size_t off_b = 0;
  auto alloc = [&](size_t bytes) {
    size_t cur = off_b;
    off_b += (bytes + 255) & ~(size_t)255;
    return (void*)(ws + cur);
  };
  __half* xl1 = (__half*)alloc((size_t)N * ROW * sizeof(__half));
  __half* xr1 = (__half*)alloc((size_t)N * ROW * sizeof(__half));
  int*   deg  = (int*)alloc((size_t)N * sizeof(int));
  int*   offp = (int*)alloc((size_t)(N + 1) * sizeof(int));
  int*   curs = (int*)alloc((size_t)N * sizeof(int));
  int*   srcs = (int*)alloc((size_t)EP * sizeof(int));
  float* xl2  = (float*)alloc((size_t)N * sizeof(float));
  float* xr2  = (float*)alloc((size_t)N * sizeof(float));
  (void)ws_size; (void)in_sizes; (void)n_in; (void)out_size;

  (void)hipMemsetAsync(deg, 0, (size_t)N * sizeof(int), stream);

  k_t1_count<<<T1_BLOCKS + CNT_BLOCKS, 512, 0, stream>>>(
      x, W1l, b1l, W1r, b1r, xl1, xr1, ei, deg);

  k_scan<<<1, 1024, 0, stream>>>(deg, offp, curs);
  k_scatter<<<(EP + 511) / 512, 512, 0, stream>>>(ei, curs, srcs);

  k_l1agg<<<(N + 3) / 4, 256, 0, stream>>>(
      offp, srcs, xl1, xr1, att1, bias1, W2l, b2l, W2r, b2r, xl2, xr2);

  k_l2agg<<<(N + 255) / 256, 256, 0, stream>>>(
      offp, srcs, xl2, xr2, att2, bias2, out);
}

// Round 6
// 156.579 us; speedup vs baseline: 3.5130x; 1.1757x over previous
//
#include <hip/hip_runtime.h>
#include <hip/hip_fp16.h>
#include <math.h>

#define N    20000
#define E    200000
#define EP   220000   // E + N self loops
#define F_IN 23
#define D1   960
#define H1   8
#define C1   120
#define KPL  15       // real channels per lane
#define PC   16       // padded channels per lane
#define ROW  1024     // halves per node row (2048 B)

typedef _Float16 f16x2 __attribute__((ext_vector_type(2)));

__device__ inline float fdot2(__half2 a, __half2 b, float c) {
#if __has_builtin(__builtin_amdgcn_fdot2)
  f16x2 av, bv;
  __builtin_memcpy(&av, &a, 4);
  __builtin_memcpy(&bv, &b, 4);
  return __builtin_amdgcn_fdot2(av, bv, c, false);
#else
  float2 af = __half22float2(a), bf = __half22float2(b);
  return fmaf(af.x, bf.x, fmaf(af.y, bf.y, c));
#endif
}

// packed half2 max (ROCm 7.2 lacks __hmax2) -> v_pk_max_f16
__device__ inline __half2 hmax2(__half2 a, __half2 b) {
  f16x2 av, bv;
  __builtin_memcpy(&av, &a, 4);
  __builtin_memcpy(&bv, &b, 4);
  f16x2 rv = __builtin_elementwise_max(av, bv);
  __half2 r;
  __builtin_memcpy(&r, &rv, 4);
  return r;
}

// ---------------- fused: transform1 (blocks 0..T1_BLOCKS) + count ----------
// transform: 512 threads; thread j owns channel pair of rlane=j>>3, kp=j&7:
// k0=2kp, k1=2kp+1 (k1==15 is the zero pad). f32 compute, packed 4B NT store.
// __launch_bounds__(512,4): VGPR cap 128 so the 92 W floats stay in registers
// (R5's build chose 56 VGPRs and re-read W from L2 every node: ~3.7GB L2).
#define T1_BLOCKS 500
#define T1_NPB    40
#define T1_TILE   20
#define CNT_BLOCKS 430   // ceil(EP/512)
__global__ __launch_bounds__(512, 4)
void k_t1_count(const float* __restrict__ x,
                const float* __restrict__ W1l, const float* __restrict__ b1l,
                const float* __restrict__ W1r, const float* __restrict__ b1r,
                __half* __restrict__ xl1, __half* __restrict__ xr1,
                const int* __restrict__ ei, int* __restrict__ deg) {
  int tid = threadIdx.x;
  if (blockIdx.x >= T1_BLOCKS) {
    int id = (blockIdx.x - T1_BLOCKS) * 512 + tid;
    if (id < EP) {
      int dst = (id < E) ? ei[E + id] : (id - E);
      atomicAdd(&deg[dst], 1);
    }
    return;
  }
  int rlane = tid >> 3, kp = tid & 7;
  int c0 = (rlane >> 3) * C1 + (rlane & 7) * KPL + 2 * kp;
  bool hasK1 = (kp < 7);
  float wl0[F_IN], wl1[F_IN], wr0[F_IN], wr1[F_IN];
#pragma unroll
  for (int f = 0; f < F_IN; f++) {
    wl0[f] = W1l[f * D1 + c0];
    wr0[f] = W1r[f * D1 + c0];
    wl1[f] = hasK1 ? W1l[f * D1 + c0 + 1] : 0.f;
    wr1[f] = hasK1 ? W1r[f * D1 + c0 + 1] : 0.f;
  }
  float bl0 = b1l[c0], br0 = b1r[c0];
  float bl1 = hasK1 ? b1l[c0 + 1] : 0.f;
  float br1 = hasK1 ? b1r[c0 + 1] : 0.f;

  __shared__ float xs[T1_TILE][F_IN];
  int nbase = blockIdx.x * T1_NPB;
  unsigned int* xl1u = (unsigned int*)xl1;
  unsigned int* xr1u = (unsigned int*)xr1;
  for (int t = 0; t < T1_NPB; t += T1_TILE) {
    if (tid < T1_TILE * F_IN) {
      int n = tid / F_IN, f = tid - n * F_IN;
      xs[n][f] = x[(size_t)(nbase + t + n) * F_IN + f];
    }
    __syncthreads();
    for (int n = 0; n < T1_TILE; n++) {
      float a0 = bl0, a1 = bl1, r0 = br0, r1 = br1;
#pragma unroll
      for (int f = 0; f < F_IN; f++) {
        float xv = xs[n][f];
        a0 = fmaf(xv, wl0[f], a0);
        a1 = fmaf(xv, wl1[f], a1);
        r0 = fmaf(xv, wr0[f], r0);
        r1 = fmaf(xv, wr1[f], r1);
      }
      size_t o = (size_t)(nbase + t + n) * 512 + tid;
      unsigned int ul = ((unsigned int)__half_as_ushort(__float2half(a1)) << 16)
                      | __half_as_ushort(__float2half(a0));
      unsigned int ur = ((unsigned int)__half_as_ushort(__float2half(r1)) << 16)
                      | __half_as_ushort(__float2half(r0));
      __builtin_nontemporal_store(ul, &xl1u[o]);
      __builtin_nontemporal_store(ur, &xr1u[o]);
    }
    __syncthreads();
  }
}

// ---------------- scan: whole deg[] in LDS, 20 elems/thread ----------------
#define SC_TOT 20480   // 1024 * 20
__global__ __launch_bounds__(1024)
void k_scan(const int* __restrict__ deg, int* __restrict__ off,
            int* __restrict__ cursor) {
  __shared__ int buf[SC_TOT];
  __shared__ int parts[1024];
  __shared__ int wsum[17];
  int tid = threadIdx.x;
  for (int i = tid; i < SC_TOT; i += 1024) buf[i] = (i < N) ? deg[i] : 0;
  __syncthreads();
  int base = tid * 20;
  int loc[20];
  int run = 0;
#pragma unroll
  for (int e = 0; e < 20; e++) { loc[e] = run; run += buf[base + e]; }
  parts[tid] = run;
  __syncthreads();
  int lane = tid & 63, wid = tid >> 6;
  int v = parts[tid];
  int incl = v;
#pragma unroll
  for (int d = 1; d < 64; d <<= 1) {
    int t = __shfl_up(incl, d, 64);
    if (lane >= d) incl += t;
  }
  if (lane == 63) wsum[wid] = incl;
  __syncthreads();
  if (tid == 0) {
    int acc = 0;
#pragma unroll
    for (int w = 0; w < 16; w++) { int t = wsum[w]; wsum[w] = acc; acc += t; }
    wsum[16] = acc;
  }
  __syncthreads();
  int texcl = incl - v + wsum[wid];
#pragma unroll
  for (int e = 0; e < 20; e++) buf[base + e] = texcl + loc[e];
  __syncthreads();
  for (int i = tid; i < N; i += 1024) {
    int t = buf[i];
    off[i] = t;
    cursor[i] = t;
  }
  if (tid == 0) off[N] = wsum[16];
}

// scatter: store src node id directly
__global__ __launch_bounds__(512)
void k_scatter(const int* __restrict__ ei, int* __restrict__ cursor,
               int* __restrict__ srcs) {
  int id = blockIdx.x * 512 + threadIdx.x;
  if (id >= EP) return;
  int dst, src;
  if (id < E) { dst = ei[E + id]; src = ei[id]; }
  else        { dst = id - E;     src = id - E; }
  int pos = atomicAdd(&cursor[dst], 1);
  srcs[pos] = src;
}

// ---------------- fused layer1 aggregate + relu + layer2 transform ----------
union Rowu {
  uint4 u[2];
  __half2 h[8];
};

__global__ __launch_bounds__(256)
void k_l1agg(const int* __restrict__ off, const int* __restrict__ srcs,
             const __half* __restrict__ xl1, const __half* __restrict__ xr1,
             const float* __restrict__ att1, const float* __restrict__ bias1,
             const float* __restrict__ W2l, const float* __restrict__ b2l,
             const float* __restrict__ W2r, const float* __restrict__ b2r,
             float* __restrict__ xl2, float* __restrict__ xr2) {
  int node = blockIdx.x * 4 + (threadIdx.x >> 6);
  if (node >= N) return;
  int lane = threadIdx.x & 63;
  int cbase = (lane >> 3) * C1 + (lane & 7) * KPL;

  Rowu xr;
  {
    const uint4* rp = (const uint4*)(xr1 + ((size_t)node << 10)) + (lane << 1);
    xr.u[0] = rp[0]; xr.u[1] = rp[1];
  }
  __half2 at2[8];
#pragma unroll
  for (int j = 0; j < 7; j++)
    at2[j] = __floats2half2_rn(att1[cbase + 2 * j], att1[cbase + 2 * j + 1]);
  at2[7] = __floats2half2_rn(att1[cbase + 14], 0.f);

  const __half2 c02 = __float2half2_rn(0.2f);
  __half2 o2[8];
#pragma unroll
  for (int j = 0; j < 8; j++) o2[j] = __float2half2_rn(0.f);
  float m = -INFINITY, d = 0.f;

  int p0 = off[node], p1 = off[node + 1];
  int sA = srcs[p0];
  int sB = srcs[(p0 + 1 < p1) ? p0 + 1 : p0];
  Rowu rA, rB;
  {
    const uint4* rp = (const uint4*)(xl1 + ((size_t)sA << 10)) + (lane << 1);
    rA.u[0] = rp[0]; rA.u[1] = rp[1];
    const uint4* np = (const uint4*)(xl1 + ((size_t)sB << 10)) + (lane << 1);
    rB.u[0] = np[0]; rB.u[1] = np[1];
  }

  for (int p = p0; p < p1; p++) {
    Rowu cur = rA;
    rA = rB;
    int pn = (p + 2 < p1) ? p + 2 : p1 - 1;
    int sn = srcs[pn];
    const uint4* np = (const uint4*)(xl1 + ((size_t)sn << 10)) + (lane << 1);
    rB.u[0] = np[0]; rB.u[1] = np[1];

    float pe = 0.f;
#pragma unroll
    for (int j = 0; j < 8; j++) {
      __half2 s = __hadd2(cur.h[j], xr.h[j]);
      __half2 l = hmax2(s, __hmul2(c02, s));   // leaky = max(s, 0.2s)
      pe = fdot2(l, at2[j], pe);
    }
    pe += __shfl_xor(pe, 1, 64);
    pe += __shfl_xor(pe, 2, 64);
    pe += __shfl_xor(pe, 4, 64);
    if (pe > m) {
      float sc = __expf(m - pe);   // m=-inf first edge -> 0
      d *= sc;
      __half2 s2 = __float2half2_rn(sc);
#pragma unroll
      for (int j = 0; j < 8; j++) o2[j] = __hmul2(o2[j], s2);
      m = pe;
    }
    float w = __expf(pe - m);
    d += w;
    __half2 w2 = __float2half2_rn(w);
#pragma unroll
    for (int j = 0; j < 8; j++) o2[j] = __hfma2(w2, cur.h[j], o2[j]);
  }

  float inv = 1.f / (d + 1e-16f);
  float pl = 0.f, pr = 0.f;
#pragma unroll
  for (int j = 0; j < 8; j++) {
    float2 of = __half22float2(o2[j]);
    int k0 = 2 * j;
    float hv = fmaf(of.x, inv, bias1[cbase + k0]);
    hv = fmaxf(hv, 0.f);
    pl = fmaf(hv, W2l[cbase + k0], pl);
    pr = fmaf(hv, W2r[cbase + k0], pr);
    if (j < 7) {
      float hv2 = fmaf(of.y, inv, bias1[cbase + k0 + 1]);
      hv2 = fmaxf(hv2, 0.f);
      pl = fmaf(hv2, W2l[cbase + k0 + 1], pl);
      pr = fmaf(hv2, W2r[cbase + k0 + 1], pr);
    }
  }
#pragma unroll
  for (int dx = 1; dx < 64; dx <<= 1) {
    pl += __shfl_xor(pl, dx, 64);
    pr += __shfl_xor(pr, dx, 64);
  }
  if (lane == 0) {
    xl2[node] = pl + b2l[0];
    xr2[node] = pr + b2r[0];
  }
}

// ---------------- layer 2 aggregate ----------------
__global__ void k_l2agg(const int* __restrict__ off, const int* __restrict__ srcs,
                        const float* __restrict__ xl2, const float* __restrict__ xr2,
                        const float* __restrict__ att2, const float* __restrict__ bias2,
                        float* __restrict__ out) {
  int node = blockIdx.x * blockDim.x + threadIdx.x;
  if (node >= N) return;
  float xr = xr2[node];
  float a2 = att2[0];
  float m = -INFINITY, d = 0.f, o = 0.f;
  int p1 = off[node + 1];
  for (int p = off[node]; p < p1; p++) {
    float xl = xl2[srcs[p]];
    float s = xl + xr;
    s = fmaxf(s, 0.2f * s);
    float e = s * a2;
    if (e > m) { float sc = __expf(m - e); d *= sc; o *= sc; m = e; }
    float w = __expf(e - m);
    d += w;
    o = fmaf(w, xl, o);
  }
  out[node] = o / (d + 1e-16f) + bias2[0];
}

extern "C" void kernel_launch(void* const* d_in, const int* in_sizes, int n_in,
                              void* d_out, int out_size, void* d_ws, size_t ws_size,
                              hipStream_t stream) {
  const float* x     = (const float*)d_in[0];
  const int*   ei    = (const int*)d_in[1];
  const float* W1l   = (const float*)d_in[2];
  const float* b1l   = (const float*)d_in[3];
  const float* W1r   = (const float*)d_in[4];
  const float* b1r   = (const float*)d_in[5];
  const float* att1  = (const float*)d_in[6];
  const float* bias1 = (const float*)d_in[7];
  const float* W2l   = (const float*)d_in[8];
  const float* b2l   = (const float*)d_in[9];
  const float* W2r   = (const float*)d_in[10];
  const float* b2r   = (const float*)d_in[11];
  const float* att2  = (const float*)d_in[12];
  const float* bias2 = (const float*)d_in[13];
  float* out = (float*)d_out;

  char* ws = (char*)d_ws;
  size_t off_b = 0;
  auto alloc = [&](size_t bytes) {
    size_t cur = off_b;
    off_b += (bytes + 255) & ~(size_t)255;
    return (void*)(ws + cur);
  };
  __half* xl1 = (__half*)alloc((size_t)N * ROW * sizeof(__half));
  __half* xr1 = (__half*)alloc((size_t)N * ROW * sizeof(__half));
  int*   deg  = (int*)alloc((size_t)N * sizeof(int));
  int*   offp = (int*)alloc((size_t)(N + 1) * sizeof(int));
  int*   curs = (int*)alloc((size_t)N * sizeof(int));
  int*   srcs = (int*)alloc((size_t)EP * sizeof(int));
  float* xl2  = (float*)alloc((size_t)N * sizeof(float));
  float* xr2  = (float*)alloc((size_t)N * sizeof(float));
  (void)ws_size; (void)in_sizes; (void)n_in; (void)out_size;

  (void)hipMemsetAsync(deg, 0, (size_t)N * sizeof(int), stream);

  k_t1_count<<<T1_BLOCKS + CNT_BLOCKS, 512, 0, stream>>>(
      x, W1l, b1l, W1r, b1r, xl1, xr1, ei, deg);

  k_scan<<<1, 1024, 0, stream>>>(deg, offp, curs);
  k_scatter<<<(EP + 511) / 512, 512, 0, stream>>>(ei, curs, srcs);

  k_l1agg<<<(N + 3) / 4, 256, 0, stream>>>(
      offp, srcs, xl1, xr1, att1, bias1, W2l, b2l, W2r, b2r, xl2, xr2);

  k_l2agg<<<(N + 255) / 256, 256, 0, stream>>>(
      offp, srcs, xl2, xr2, att2, bias2, out);
}